// Round 1
// baseline (433.794 us; speedup 1.0000x reference)
//
#include <hip/hip_runtime.h>
#include <cstdint>

typedef __bf16 bf16x8 __attribute__((ext_vector_type(8)));
typedef float f32x4 __attribute__((ext_vector_type(4)));

#define DIM 512
#define TSEQ 4096

__device__ __forceinline__ ushort f2bf(float x) {
  uint32_t u = __float_as_uint(x);
  u += 0x7fffu + ((u >> 16) & 1u);
  return (ushort)(u >> 16);
}

// ---------------- gates: gq = sigm(qv), gk = sigm(kv), gv = sigm(vv@Ws^T+bs)*tanh(vv@Wt^T+bt)
__global__ __launch_bounds__(512)
void gates_kernel(const float* __restrict__ qv, const float* __restrict__ kv,
                  const float* __restrict__ vvec,
                  const float* __restrict__ Ws, const float* __restrict__ bs,
                  const float* __restrict__ Wt, const float* __restrict__ bt,
                  float* __restrict__ gq, float* __restrict__ gk, float* __restrict__ gv) {
  __shared__ float vv[DIM];
  int d = threadIdx.x;
  vv[d] = 1.f / (1.f + __expf(-vvec[d]));
  __syncthreads();
  float as = bs[d], at = bt[d];
  const float* wsr = Ws + (size_t)d * DIM;
  const float* wtr = Wt + (size_t)d * DIM;
  for (int j = 0; j < DIM; ++j) {
    float x = vv[j];
    as += x * wsr[j];
    at += x * wtr[j];
  }
  float sg = 1.f / (1.f + __expf(-as));
  float th = tanhf(at);
  gq[d] = 1.f / (1.f + __expf(-qv[d]));
  gk[d] = 1.f / (1.f + __expf(-kv[d]));
  gv[d] = sg * th;
}

// ---------------- q GEMM: C[M=16384][512] = A @ Wq^T + bq (f32 out, bf16 MFMA inside)
__global__ __launch_bounds__(256)
void qgemm_kernel(const float* __restrict__ A, const float* __restrict__ W,
                  const float* __restrict__ bq, float* __restrict__ C) {
  __shared__ ushort As[64][32], Bs[64][32];
  const int t = threadIdx.x;
  const int lane = t & 63;
  const int w = t >> 6;
  const int r16 = lane & 15, kb8 = lane >> 4;
  const int rowbase = blockIdx.x * 64, colbase = blockIdx.y * 64;
  const int wr = (w >> 1) * 32, wc = (w & 1) * 32;
  f32x4 acc[2][2];
  for (int m = 0; m < 2; ++m) for (int n = 0; n < 2; ++n) acc[m][n] = (f32x4)0.f;
  const int ar = t >> 2, acCol = (t & 3) * 8;
  for (int kb = 0; kb < 16; ++kb) {
    const int k0 = kb * 32;
    __syncthreads();
    {
      const float* srcA = A + (size_t)(rowbase + ar) * DIM + k0 + acCol;
      float4 a0 = ((const float4*)srcA)[0], a1 = ((const float4*)srcA)[1];
      ushort4 u0 = { f2bf(a0.x), f2bf(a0.y), f2bf(a0.z), f2bf(a0.w) };
      ushort4 u1 = { f2bf(a1.x), f2bf(a1.y), f2bf(a1.z), f2bf(a1.w) };
      ((ushort4*)&As[ar][acCol])[0] = u0;
      ((ushort4*)&As[ar][acCol])[1] = u1;
      const float* srcB = W + (size_t)(colbase + ar) * DIM + k0 + acCol;
      float4 b0 = ((const float4*)srcB)[0], b1 = ((const float4*)srcB)[1];
      ushort4 v0 = { f2bf(b0.x), f2bf(b0.y), f2bf(b0.z), f2bf(b0.w) };
      ushort4 v1 = { f2bf(b1.x), f2bf(b1.y), f2bf(b1.z), f2bf(b1.w) };
      ((ushort4*)&Bs[ar][acCol])[0] = v0;
      ((ushort4*)&Bs[ar][acCol])[1] = v1;
    }
    __syncthreads();
    bf16x8 a[2], bb[2];
    for (int m = 0; m < 2; ++m) a[m] = *(const bf16x8*)&As[wr + m*16 + r16][kb8*8];
    for (int n = 0; n < 2; ++n) bb[n] = *(const bf16x8*)&Bs[wc + n*16 + r16][kb8*8];
    for (int m = 0; m < 2; ++m)
      for (int n = 0; n < 2; ++n)
        acc[m][n] = __builtin_amdgcn_mfma_f32_16x16x32_bf16(a[m], bb[n], acc[m][n], 0, 0, 0);
  }
  for (int m = 0; m < 2; ++m)
    for (int n = 0; n < 2; ++n)
      for (int r = 0; r < 4; ++r) {
        int row = rowbase + wr + m*16 + kb8*4 + r;
        int col = colbase + wc + n*16 + r16;
        C[(size_t)row * DIM + col] = acc[m][n][r] + bq[col];
      }
}

// ---------------- LayerNorm + gamma/beta + sigmoid(query_vector) gate + 1/sqrt(D) + bf16
__global__ __launch_bounds__(256)
void lnq_kernel(const float* __restrict__ q, const float* __restrict__ gamma,
                const float* __restrict__ beta, const float* __restrict__ gq,
                ushort* __restrict__ qout) {
  const int lane = threadIdx.x & 63;
  const size_t row = (size_t)blockIdx.x * 4 + (threadIdx.x >> 6);
  const float* src = q + row * DIM;
  float4 x0 = ((const float4*)src)[lane * 2];
  float4 x1 = ((const float4*)src)[lane * 2 + 1];
  float s = x0.x + x0.y + x0.z + x0.w + x1.x + x1.y + x1.z + x1.w;
  float ss = x0.x*x0.x + x0.y*x0.y + x0.z*x0.z + x0.w*x0.w
           + x1.x*x1.x + x1.y*x1.y + x1.z*x1.z + x1.w*x1.w;
  for (int off = 1; off < 64; off <<= 1) {
    s  += __shfl_xor(s, off, 64);
    ss += __shfl_xor(ss, off, 64);
  }
  const float mu = s * (1.f / DIM);
  const float var = ss * (1.f / DIM) - mu * mu;
  const float rs = rsqrtf(var + 1e-5f);
  const int c0 = lane * 8;
  float4 g0 = *(const float4*)(gamma + c0), g1 = *(const float4*)(gamma + c0 + 4);
  float4 b0 = *(const float4*)(beta + c0),  b1 = *(const float4*)(beta + c0 + 4);
  float4 q0 = *(const float4*)(gq + c0),    q1 = *(const float4*)(gq + c0 + 4);
  const float SC = 0.044194173824159216f;  // 1/sqrt(512)
  ushort4 o0 = { f2bf(((x0.x-mu)*rs*g0.x + b0.x) * q0.x * SC),
                 f2bf(((x0.y-mu)*rs*g0.y + b0.y) * q0.y * SC),
                 f2bf(((x0.z-mu)*rs*g0.z + b0.z) * q0.z * SC),
                 f2bf(((x0.w-mu)*rs*g0.w + b0.w) * q0.w * SC) };
  ushort4 o1 = { f2bf(((x1.x-mu)*rs*g1.x + b1.x) * q1.x * SC),
                 f2bf(((x1.y-mu)*rs*g1.y + b1.y) * q1.y * SC),
                 f2bf(((x1.z-mu)*rs*g1.z + b1.z) * q1.z * SC),
                 f2bf(((x1.w-mu)*rs*g1.w + b1.w) * q1.w * SC) };
  ushort* dst = qout + row * DIM + c0;
  ((ushort4*)dst)[0] = o0;
  ((ushort4*)dst)[1] = o1;
}

// ---------------- k = bf16(value * gk)  (row-major)
__global__ __launch_bounds__(256)
void kprep_kernel(const float* __restrict__ value, const float* __restrict__ gk,
                  ushort* __restrict__ kbuf) {
  int i = blockIdx.x * 256 + threadIdx.x;
  float4 v = ((const float4*)value)[i];
  float4 g = ((const float4*)gk)[i & 127];
  ushort4 o = { f2bf(v.x*g.x), f2bf(v.y*g.y), f2bf(v.z*g.z), f2bf(v.w*g.w) };
  ((ushort4*)kbuf)[i] = o;
}

// ---------------- vT[b][d][t] = bf16(value[b][t][d] * gv[d])
__global__ __launch_bounds__(256)
void vtrans_kernel(const float* __restrict__ value, const float* __restrict__ gv,
                   ushort* __restrict__ vT) {
  __shared__ ushort tile[64][73];
  const int t = threadIdx.x;
  const int s0 = blockIdx.x * 64, d0 = blockIdx.y * 64;
  const size_t boff = (size_t)blockIdx.z * TSEQ * DIM;
  for (int rep = 0; rep < 4; ++rep) {
    int f = rep * 1024 + t * 4;
    int s = f >> 6, dc = f & 63;
    float4 v = *(const float4*)(value + boff + (size_t)(s0 + s) * DIM + d0 + dc);
    float4 g = *(const float4*)(gv + d0 + dc);
    tile[s][dc]     = f2bf(v.x * g.x);
    tile[s][dc + 1] = f2bf(v.y * g.y);
    tile[s][dc + 2] = f2bf(v.z * g.z);
    tile[s][dc + 3] = f2bf(v.w * g.w);
  }
  __syncthreads();
  const int d = t >> 2, sc0 = (t & 3) * 16;
  __align__(16) ushort tmp[16];
  #pragma unroll
  for (int j = 0; j < 16; ++j) tmp[j] = tile[sc0 + j][d];
  ushort* dst = vT + (size_t)blockIdx.z * DIM * TSEQ + (size_t)(d0 + d) * TSEQ + s0 + sc0;
  ((uint4*)dst)[0] = *(const uint4*)&tmp[0];
  ((uint4*)dst)[1] = *(const uint4*)&tmp[8];
}

// ---------------- causal flash attention, QB=32 rows/wg, KVB=64/iter, 8 waves
// waves: (dcQ = w&3) 128-wide D chunk for QK^T partials; (h = w>>2) KV half.
// PV: wave w owns 64-wide D chunk of O.
__global__ __launch_bounds__(512)
void attn_kernel(const ushort* __restrict__ qb, const ushort* __restrict__ kb,
                 const ushort* __restrict__ vT, float* __restrict__ out) {
  __shared__ float Sp[4][32][68];     // padded: write 2-way, read minimum
  __shared__ ushort P[32][72];        // padded, 16B-aligned rows
  __shared__ float mrow[32], lrow[32], arow[32];

  const int t = threadIdx.x;
  const int lane = t & 63;
  const int w = t >> 6;
  const int r16 = lane & 15;
  const int kb8 = lane >> 4;
  const int dcQ = w & 3;
  const int h = w >> 2;
  const int b = blockIdx.x >> 6;
  const int pr = blockIdx.x & 63;
  const size_t boff  = (size_t)b * TSEQ * DIM;
  const size_t vboff = (size_t)b * DIM * TSEQ;

  for (int pass = 0; pass < 2; ++pass) {
    const int qt = pass ? (127 - pr) : pr;   // balanced pair: work = (qt>>1)+1 sums to 65
    const int qbase = qt * 32;
    if (t < 32) { mrow[t] = -1e30f; lrow[t] = 0.f; }
    bf16x8 aQ[2][4];
    for (int m = 0; m < 2; ++m)
      for (int c = 0; c < 4; ++c)
        aQ[m][c] = *(const bf16x8*)(qb + boff + (size_t)(qbase + m*16 + r16) * DIM
                                    + dcQ*128 + c*32 + kb8*8);
    f32x4 accO[2][4];
    for (int m = 0; m < 2; ++m) for (int n = 0; n < 4; ++n) accO[m][n] = (f32x4)0.f;
    __syncthreads();

    const int nkt = (qt >> 1) + 1;
    for (int kt = 0; kt < nkt; ++kt) {
      const int kbase = kt * 64;
      // --- QK^T partial over this wave's 128-wide D chunk, 32 KV rows (half h)
      f32x4 accS[2][2];
      for (int m = 0; m < 2; ++m) for (int n = 0; n < 2; ++n) accS[m][n] = (f32x4)0.f;
      #pragma unroll
      for (int c = 0; c < 4; ++c) {
        bf16x8 bK0 = *(const bf16x8*)(kb + boff + (size_t)(kbase + h*32 + r16) * DIM
                                      + dcQ*128 + c*32 + kb8*8);
        bf16x8 bK1 = *(const bf16x8*)(kb + boff + (size_t)(kbase + h*32 + 16 + r16) * DIM
                                      + dcQ*128 + c*32 + kb8*8);
        for (int m = 0; m < 2; ++m) {
          accS[m][0] = __builtin_amdgcn_mfma_f32_16x16x32_bf16(aQ[m][c], bK0, accS[m][0], 0, 0, 0);
          accS[m][1] = __builtin_amdgcn_mfma_f32_16x16x32_bf16(aQ[m][c], bK1, accS[m][1], 0, 0, 0);
        }
      }
      #pragma unroll
      for (int m = 0; m < 2; ++m)
        for (int n = 0; n < 2; ++n)
          for (int r = 0; r < 4; ++r)
            Sp[dcQ][m*16 + kb8*4 + r][h*32 + n*16 + r16] = accS[m][n][r];
      __syncthreads();
      // --- cross-wave reduce + mask + online softmax (16 threads per row)
      {
        const int row = t >> 4, c0 = (t & 15) * 4;
        float4 s0v = *(const float4*)&Sp[0][row][c0];
        float4 s1v = *(const float4*)&Sp[1][row][c0];
        float4 s2v = *(const float4*)&Sp[2][row][c0];
        float4 s3v = *(const float4*)&Sp[3][row][c0];
        float s[4] = { s0v.x + s1v.x + s2v.x + s3v.x,
                       s0v.y + s1v.y + s2v.y + s3v.y,
                       s0v.z + s1v.z + s2v.z + s3v.z,
                       s0v.w + s1v.w + s2v.w + s3v.w };
        const int qg = qbase + row;
        #pragma unroll
        for (int j = 0; j < 4; ++j)
          if (kbase + c0 + j > qg) s[j] = -1e30f;
        float pm = fmaxf(fmaxf(s[0], s[1]), fmaxf(s[2], s[3]));
        #pragma unroll
        for (int off = 1; off < 16; off <<= 1)
          pm = fmaxf(pm, __shfl_xor(pm, off, 64));
        float mold = mrow[row];
        float mnew = fmaxf(mold, pm);
        float p[4]; float ps = 0.f;
        #pragma unroll
        for (int j = 0; j < 4; ++j) { p[j] = __expf(s[j] - mnew); ps += p[j]; }
        #pragma unroll
        for (int off = 1; off < 16; off <<= 1)
          ps += __shfl_xor(ps, off, 64);
        ushort4 pb = { f2bf(p[0]), f2bf(p[1]), f2bf(p[2]), f2bf(p[3]) };
        *(ushort4*)&P[row][c0] = pb;
        if ((t & 15) == 0) {
          float al = __expf(mold - mnew);
          arow[row] = al;
          mrow[row] = mnew;
          lrow[row] = lrow[row] * al + ps;
        }
      }
      __syncthreads();
      // --- rescale O, then PV over this wave's 64-wide D chunk
      #pragma unroll
      for (int m = 0; m < 2; ++m)
        for (int r = 0; r < 4; ++r) {
          float al = arow[m*16 + kb8*4 + r];
          for (int n = 0; n < 4; ++n) accO[m][n][r] *= al;
        }
      #pragma unroll
      for (int c = 0; c < 2; ++c) {
        bf16x8 aP0 = *(const bf16x8*)&P[r16][c*32 + kb8*8];
        bf16x8 aP1 = *(const bf16x8*)&P[16 + r16][c*32 + kb8*8];
        for (int n = 0; n < 4; ++n) {
          bf16x8 bV = *(const bf16x8*)(vT + vboff + (size_t)(w*64 + n*16 + r16) * TSEQ
                                       + kbase + c*32 + kb8*8);
          accO[0][n] = __builtin_amdgcn_mfma_f32_16x16x32_bf16(aP0, bV, accO[0][n], 0, 0, 0);
          accO[1][n] = __builtin_amdgcn_mfma_f32_16x16x32_bf16(aP1, bV, accO[1][n], 0, 0, 0);
        }
      }
    }
    // --- epilogue: divide by l, write f32
    for (int m = 0; m < 2; ++m)
      for (int r = 0; r < 4; ++r) {
        int row = m*16 + kb8*4 + r;
        float inv = 1.f / lrow[row];
        float* dst = out + boff + (size_t)(qbase + row) * DIM + w*64 + r16;
        #pragma unroll
        for (int n = 0; n < 4; ++n)
          dst[n*16] = accO[m][n][r] * inv;
      }
    __syncthreads();  // protect lrow/mrow from next pass's init
  }
}

extern "C" void kernel_launch(void* const* d_in, const int* in_sizes, int n_in,
                              void* d_out, int out_size, void* d_ws, size_t ws_size,
                              hipStream_t stream) {
  const float* query = (const float*)d_in[0];
  const float* value = (const float*)d_in[1];
  const float* qv    = (const float*)d_in[2];
  const float* kv    = (const float*)d_in[3];
  const float* vvec  = (const float*)d_in[4];
  const float* Wq    = (const float*)d_in[5];
  const float* bq    = (const float*)d_in[6];
  const float* gam   = (const float*)d_in[7];
  const float* bet   = (const float*)d_in[8];
  const float* Ws    = (const float*)d_in[9];
  const float* bs    = (const float*)d_in[10];
  const float* Wt    = (const float*)d_in[11];
  const float* bt    = (const float*)d_in[12];
  float* out = (float*)d_out;

  char* ws = (char*)d_ws;
  float*  gq = (float*)(ws);
  float*  gk = (float*)(ws + 2048);
  float*  gv = (float*)(ws + 4096);
  float*  qf = (float*)(ws + 8192);                               // 16384x512 f32
  ushort* qb = (ushort*)(ws + 8192 + 33554432);                   // bf16
  ushort* kb = (ushort*)(ws + 8192 + 33554432 + 16777216);        // bf16
  ushort* vT = (ushort*)(ws + 8192 + 33554432 + 2*16777216);      // bf16 transposed

  gates_kernel<<<1, 512, 0, stream>>>(qv, kv, vvec, Ws, bs, Wt, bt, gq, gk, gv);
  qgemm_kernel<<<dim3(256, 8), 256, 0, stream>>>(query, Wq, bq, qf);
  lnq_kernel<<<4096, 256, 0, stream>>>(qf, gam, bet, gq, qb);
  kprep_kernel<<<8192, 256, 0, stream>>>(value, gk, kb);
  vtrans_kernel<<<dim3(64, 8, 4), 256, 0, stream>>>(value, gv, vT);
  attn_kernel<<<256, 512, 0, stream>>>(qb, kb, vT, out);
}

// Round 2
// 308.765 us; speedup vs baseline: 1.4049x; 1.4049x over previous
//
#include <hip/hip_runtime.h>
#include <cstdint>

typedef __bf16 bf16x8 __attribute__((ext_vector_type(8)));
typedef float f32x4 __attribute__((ext_vector_type(4)));

#define DIM 512
#define TSEQ 4096

__device__ __forceinline__ ushort f2bf(float x) {
  uint32_t u = __float_as_uint(x);
  u += 0x7fffu + ((u >> 16) & 1u);
  return (ushort)(u >> 16);
}

// ---------------- gates
__global__ __launch_bounds__(512)
void gates_kernel(const float* __restrict__ qv, const float* __restrict__ kv,
                  const float* __restrict__ vvec,
                  const float* __restrict__ Ws, const float* __restrict__ bs,
                  const float* __restrict__ Wt, const float* __restrict__ bt,
                  float* __restrict__ gq, float* __restrict__ gk, float* __restrict__ gv) {
  __shared__ float vv[DIM];
  int d = threadIdx.x;
  vv[d] = 1.f / (1.f + __expf(-vvec[d]));
  __syncthreads();
  float as = bs[d], at = bt[d];
  const float* wsr = Ws + (size_t)d * DIM;
  const float* wtr = Wt + (size_t)d * DIM;
  for (int j = 0; j < DIM; ++j) {
    float x = vv[j];
    as += x * wsr[j];
    at += x * wtr[j];
  }
  float sg = 1.f / (1.f + __expf(-as));
  float th = tanhf(at);
  gq[d] = 1.f / (1.f + __expf(-qv[d]));
  gk[d] = 1.f / (1.f + __expf(-kv[d]));
  gv[d] = sg * th;
}

// ---------------- q GEMM: C = A @ Wq^T + bq (f32 out)
__global__ __launch_bounds__(256)
void qgemm_kernel(const float* __restrict__ A, const float* __restrict__ W,
                  const float* __restrict__ bq, float* __restrict__ C) {
  __shared__ ushort As[64][32], Bs[64][32];
  const int t = threadIdx.x;
  const int lane = t & 63;
  const int w = t >> 6;
  const int r16 = lane & 15, kb8 = lane >> 4;
  const int rowbase = blockIdx.x * 64, colbase = blockIdx.y * 64;
  const int wr = (w >> 1) * 32, wc = (w & 1) * 32;
  f32x4 acc[2][2];
  for (int m = 0; m < 2; ++m) for (int n = 0; n < 2; ++n) acc[m][n] = (f32x4)0.f;
  const int ar = t >> 2, acCol = (t & 3) * 8;
  for (int kb = 0; kb < 16; ++kb) {
    const int k0 = kb * 32;
    __syncthreads();
    {
      const float* srcA = A + (size_t)(rowbase + ar) * DIM + k0 + acCol;
      float4 a0 = ((const float4*)srcA)[0], a1 = ((const float4*)srcA)[1];
      ushort4 u0 = { f2bf(a0.x), f2bf(a0.y), f2bf(a0.z), f2bf(a0.w) };
      ushort4 u1 = { f2bf(a1.x), f2bf(a1.y), f2bf(a1.z), f2bf(a1.w) };
      ((ushort4*)&As[ar][acCol])[0] = u0;
      ((ushort4*)&As[ar][acCol])[1] = u1;
      const float* srcB = W + (size_t)(colbase + ar) * DIM + k0 + acCol;
      float4 b0 = ((const float4*)srcB)[0], b1 = ((const float4*)srcB)[1];
      ushort4 v0 = { f2bf(b0.x), f2bf(b0.y), f2bf(b0.z), f2bf(b0.w) };
      ushort4 v1 = { f2bf(b1.x), f2bf(b1.y), f2bf(b1.z), f2bf(b1.w) };
      ((ushort4*)&Bs[ar][acCol])[0] = v0;
      ((ushort4*)&Bs[ar][acCol])[1] = v1;
    }
    __syncthreads();
    bf16x8 a[2], bb[2];
    for (int m = 0; m < 2; ++m) a[m] = *(const bf16x8*)&As[wr + m*16 + r16][kb8*8];
    for (int n = 0; n < 2; ++n) bb[n] = *(const bf16x8*)&Bs[wc + n*16 + r16][kb8*8];
    for (int m = 0; m < 2; ++m)
      for (int n = 0; n < 2; ++n)
        acc[m][n] = __builtin_amdgcn_mfma_f32_16x16x32_bf16(a[m], bb[n], acc[m][n], 0, 0, 0);
  }
  for (int m = 0; m < 2; ++m)
    for (int n = 0; n < 2; ++n)
      for (int r = 0; r < 4; ++r) {
        int row = rowbase + wr + m*16 + kb8*4 + r;
        int col = colbase + wc + n*16 + r16;
        C[(size_t)row * DIM + col] = acc[m][n][r] + bq[col];
      }
}

// ---------------- LayerNorm + gate + scale + bf16
__global__ __launch_bounds__(256)
void lnq_kernel(const float* __restrict__ q, const float* __restrict__ gamma,
                const float* __restrict__ beta, const float* __restrict__ gq,
                ushort* __restrict__ qout) {
  const int lane = threadIdx.x & 63;
  const size_t row = (size_t)blockIdx.x * 4 + (threadIdx.x >> 6);
  const float* src = q + row * DIM;
  float4 x0 = ((const float4*)src)[lane * 2];
  float4 x1 = ((const float4*)src)[lane * 2 + 1];
  float s = x0.x + x0.y + x0.z + x0.w + x1.x + x1.y + x1.z + x1.w;
  float ss = x0.x*x0.x + x0.y*x0.y + x0.z*x0.z + x0.w*x0.w
           + x1.x*x1.x + x1.y*x1.y + x1.z*x1.z + x1.w*x1.w;
  for (int off = 1; off < 64; off <<= 1) {
    s  += __shfl_xor(s, off, 64);
    ss += __shfl_xor(ss, off, 64);
  }
  const float mu = s * (1.f / DIM);
  const float var = ss * (1.f / DIM) - mu * mu;
  const float rs = rsqrtf(var + 1e-5f);
  const int c0 = lane * 8;
  float4 g0 = *(const float4*)(gamma + c0), g1 = *(const float4*)(gamma + c0 + 4);
  float4 b0 = *(const float4*)(beta + c0),  b1 = *(const float4*)(beta + c0 + 4);
  float4 q0 = *(const float4*)(gq + c0),    q1 = *(const float4*)(gq + c0 + 4);
  const float SC = 0.044194173824159216f;  // 1/sqrt(512)
  ushort4 o0 = { f2bf(((x0.x-mu)*rs*g0.x + b0.x) * q0.x * SC),
                 f2bf(((x0.y-mu)*rs*g0.y + b0.y) * q0.y * SC),
                 f2bf(((x0.z-mu)*rs*g0.z + b0.z) * q0.z * SC),
                 f2bf(((x0.w-mu)*rs*g0.w + b0.w) * q0.w * SC) };
  ushort4 o1 = { f2bf(((x1.x-mu)*rs*g1.x + b1.x) * q1.x * SC),
                 f2bf(((x1.y-mu)*rs*g1.y + b1.y) * q1.y * SC),
                 f2bf(((x1.z-mu)*rs*g1.z + b1.z) * q1.z * SC),
                 f2bf(((x1.w-mu)*rs*g1.w + b1.w) * q1.w * SC) };
  ushort* dst = qout + row * DIM + c0;
  ((ushort4*)dst)[0] = o0;
  ((ushort4*)dst)[1] = o1;
}

// ---------------- fused: kb = bf16(value*gk) row-major; vT[b][d][t] = bf16(value*gv)
__global__ __launch_bounds__(256)
void vkprep_kernel(const float* __restrict__ value, const float* __restrict__ gk,
                   const float* __restrict__ gv,
                   ushort* __restrict__ kbuf, ushort* __restrict__ vT) {
  __shared__ ushort tile[64][73];
  const int t = threadIdx.x;
  const int s0 = blockIdx.x * 64, d0 = blockIdx.y * 64;
  const size_t boff = (size_t)blockIdx.z * TSEQ * DIM;
  #pragma unroll
  for (int rep = 0; rep < 4; ++rep) {
    int f = rep * 1024 + t * 4;
    int sr = f >> 6, dc = f & 63;
    float4 v = *(const float4*)(value + boff + (size_t)(s0 + sr) * DIM + d0 + dc);
    float4 g = *(const float4*)(gv + d0 + dc);
    float4 gg = *(const float4*)(gk + d0 + dc);
    tile[sr][dc]     = f2bf(v.x * g.x);
    tile[sr][dc + 1] = f2bf(v.y * g.y);
    tile[sr][dc + 2] = f2bf(v.z * g.z);
    tile[sr][dc + 3] = f2bf(v.w * g.w);
    ushort4 ko = { f2bf(v.x*gg.x), f2bf(v.y*gg.y), f2bf(v.z*gg.z), f2bf(v.w*gg.w) };
    *(ushort4*)(kbuf + boff + (size_t)(s0 + sr) * DIM + d0 + dc) = ko;
  }
  __syncthreads();
  const int d = t >> 2, sc0 = (t & 3) * 16;
  __align__(16) ushort tmp[16];
  #pragma unroll
  for (int j = 0; j < 16; ++j) tmp[j] = tile[sc0 + j][d];
  ushort* dst = vT + (size_t)blockIdx.z * DIM * TSEQ + (size_t)(d0 + d) * TSEQ + s0 + sc0;
  ((uint4*)dst)[0] = *(const uint4*)&tmp[0];
  ((uint4*)dst)[1] = *(const uint4*)&tmp[8];
}

// ---------------- causal flash attention, QB=64, KVB=64, 8 waves, split-pair balancing
// per batch: 32 pairs (s, 63-s). WG half 0: small tile s fully (direct out) +
// large tile (63-s) kv prefix [0, 31-s) -> partial. half 1: large tile suffix
// [31-s, 64-s) -> partial. Partials merged by comb_kernel.
__global__ __launch_bounds__(512)
void attn2_kernel(const ushort* __restrict__ qb, const ushort* __restrict__ kb,
                  const ushort* __restrict__ vT, float* __restrict__ out,
                  float* __restrict__ pO, float* __restrict__ stats) {
  __shared__ __align__(16) float Sp[4][64][68];   // 69.6 KB partial-S
  __shared__ __align__(16) ushort P[64][72];      // 9.2 KB
  __shared__ float mrow[64], lrow[64], arow[64];

  const int t = threadIdx.x;
  const int lane = t & 63;
  const int w = t >> 6;
  const int r16 = lane & 15;
  const int kb8 = lane >> 4;
  const int dcQ = w & 3;
  const int h = w >> 2;

  const int bid = blockIdx.x;
  const int wg = ((bid & 7) << 5) | (bid >> 3);   // XCD-chunked swizzle (256 = 8*32)
  const int b = wg >> 6;
  const int rr = wg & 63;
  const int s = rr >> 1;
  const int half = rr & 1;

  const size_t boff  = (size_t)b * TSEQ * DIM;
  const size_t vboff = (size_t)b * DIM * TSEQ;

  for (int ji = 0; ji < 2; ++ji) {
    int qt, kt0, kt1, mode, cid;
    if (half) {
      if (ji) break;
      qt = 63 - s; kt0 = 31 - s; kt1 = 64 - s; mode = 1; cid = (b*32 + s)*2 + 1;
    } else if (ji == 0) {
      qt = s; kt0 = 0; kt1 = s + 1; mode = 0; cid = 0;
    } else {
      qt = 63 - s; kt0 = 0; kt1 = 31 - s; mode = 1; cid = (b*32 + s)*2;
    }
    const int qbase = qt * 64;

    __syncthreads();
    if (t < 64) { mrow[t] = -1e30f; lrow[t] = 0.f; }
    bf16x8 aQ[4][4];
    #pragma unroll
    for (int m = 0; m < 4; ++m)
      #pragma unroll
      for (int c = 0; c < 4; ++c)
        aQ[m][c] = *(const bf16x8*)(qb + boff + (size_t)(qbase + m*16 + r16) * DIM
                                    + dcQ*128 + c*32 + kb8*8);
    f32x4 accO[4][4];
    #pragma unroll
    for (int m = 0; m < 4; ++m)
      #pragma unroll
      for (int n = 0; n < 4; ++n) accO[m][n] = (f32x4)0.f;
    __syncthreads();

    for (int kt = kt0; kt < kt1; ++kt) {
      const int kbase = kt * 64;
      // --- QK^T partials: this wave covers D chunk dcQ(128) x KV half h(32 rows)
      f32x4 accS[4][2];
      #pragma unroll
      for (int m = 0; m < 4; ++m) { accS[m][0] = (f32x4)0.f; accS[m][1] = (f32x4)0.f; }
      #pragma unroll
      for (int c = 0; c < 4; ++c) {
        bf16x8 bK0 = *(const bf16x8*)(kb + boff + (size_t)(kbase + h*32 + r16) * DIM
                                      + dcQ*128 + c*32 + kb8*8);
        bf16x8 bK1 = *(const bf16x8*)(kb + boff + (size_t)(kbase + h*32 + 16 + r16) * DIM
                                      + dcQ*128 + c*32 + kb8*8);
        #pragma unroll
        for (int m = 0; m < 4; ++m) {
          accS[m][0] = __builtin_amdgcn_mfma_f32_16x16x32_bf16(aQ[m][c], bK0, accS[m][0], 0, 0, 0);
          accS[m][1] = __builtin_amdgcn_mfma_f32_16x16x32_bf16(aQ[m][c], bK1, accS[m][1], 0, 0, 0);
        }
      }
      #pragma unroll
      for (int m = 0; m < 4; ++m)
        #pragma unroll
        for (int n = 0; n < 2; ++n)
          #pragma unroll
          for (int r = 0; r < 4; ++r)
            Sp[dcQ][m*16 + kb8*4 + r][h*32 + n*16 + r16] = accS[m][n][r];
      __syncthreads();
      // --- reduce 4 D-chunks + mask + online softmax: 8 threads per row
      {
        const int row = t >> 3, c0 = (t & 7) * 8;
        float sv[8];
        #pragma unroll
        for (int j = 0; j < 8; ++j) sv[j] = 0.f;
        #pragma unroll
        for (int ch = 0; ch < 4; ++ch) {
          float4 u0 = *(const float4*)&Sp[ch][row][c0];
          float4 u1 = *(const float4*)&Sp[ch][row][c0 + 4];
          sv[0] += u0.x; sv[1] += u0.y; sv[2] += u0.z; sv[3] += u0.w;
          sv[4] += u1.x; sv[5] += u1.y; sv[6] += u1.z; sv[7] += u1.w;
        }
        const int qg = qbase + row;
        #pragma unroll
        for (int j = 0; j < 8; ++j)
          if (kbase + c0 + j > qg) sv[j] = -1e30f;
        float pm = sv[0];
        #pragma unroll
        for (int j = 1; j < 8; ++j) pm = fmaxf(pm, sv[j]);
        pm = fmaxf(pm, __shfl_xor(pm, 1, 64));
        pm = fmaxf(pm, __shfl_xor(pm, 2, 64));
        pm = fmaxf(pm, __shfl_xor(pm, 4, 64));
        float mold = mrow[row];
        float mnew = fmaxf(mold, pm);
        float ps = 0.f;
        #pragma unroll
        for (int j = 0; j < 8; ++j) { sv[j] = __expf(sv[j] - mnew); ps += sv[j]; }
        ps += __shfl_xor(ps, 1, 64);
        ps += __shfl_xor(ps, 2, 64);
        ps += __shfl_xor(ps, 4, 64);
        ushort4 p0 = { f2bf(sv[0]), f2bf(sv[1]), f2bf(sv[2]), f2bf(sv[3]) };
        ushort4 p1 = { f2bf(sv[4]), f2bf(sv[5]), f2bf(sv[6]), f2bf(sv[7]) };
        *(ushort4*)&P[row][c0] = p0;
        *(ushort4*)&P[row][c0 + 4] = p1;
        if ((t & 7) == 0) {
          float al = __expf(mold - mnew);
          arow[row] = al;
          mrow[row] = mnew;
          lrow[row] = lrow[row] * al + ps;
        }
      }
      __syncthreads();
      // --- rescale O, PV: wave owns D cols [w*64, w*64+64)
      #pragma unroll
      for (int m = 0; m < 4; ++m)
        #pragma unroll
        for (int r = 0; r < 4; ++r) {
          float al = arow[m*16 + kb8*4 + r];
          #pragma unroll
          for (int n = 0; n < 4; ++n) accO[m][n][r] *= al;
        }
      #pragma unroll
      for (int c = 0; c < 2; ++c) {
        bf16x8 aP[4];
        #pragma unroll
        for (int m = 0; m < 4; ++m) aP[m] = *(const bf16x8*)&P[m*16 + r16][c*32 + kb8*8];
        #pragma unroll
        for (int n = 0; n < 4; ++n) {
          bf16x8 bV = *(const bf16x8*)(vT + vboff + (size_t)(w*64 + n*16 + r16) * TSEQ
                                       + kbase + c*32 + kb8*8);
          #pragma unroll
          for (int m = 0; m < 4; ++m)
            accO[m][n] = __builtin_amdgcn_mfma_f32_16x16x32_bf16(aP[m], bV, accO[m][n], 0, 0, 0);
        }
      }
    }
    // --- epilogue
    if (mode == 0) {
      #pragma unroll
      for (int m = 0; m < 4; ++m)
        #pragma unroll
        for (int r = 0; r < 4; ++r) {
          int row = m*16 + kb8*4 + r;
          float inv = 1.f / lrow[row];
          float* dst = out + boff + (size_t)(qbase + row) * DIM + w*64 + r16;
          #pragma unroll
          for (int n = 0; n < 4; ++n) dst[n*16] = accO[m][n][r] * inv;
        }
    } else {
      float* po = pO + (size_t)cid * (64 * DIM);
      #pragma unroll
      for (int m = 0; m < 4; ++m)
        #pragma unroll
        for (int r = 0; r < 4; ++r) {
          int row = m*16 + kb8*4 + r;
          float* dst = po + (size_t)row * DIM + w*64 + r16;
          #pragma unroll
          for (int n = 0; n < 4; ++n) dst[n*16] = accO[m][n][r];
        }
      if (t < 64) {
        stats[((size_t)cid*64 + t)*2]     = mrow[t];
        stats[((size_t)cid*64 + t)*2 + 1] = lrow[t];
      }
    }
  }
}

// ---------------- combine the two partials of each large q-tile
__global__ __launch_bounds__(256)
void comb_kernel(const float* __restrict__ pO, const float* __restrict__ stats,
                 float* __restrict__ out) {
  const int p = blockIdx.x;       // 0..127: (b, s)
  const int g = blockIdx.y;       // 0..15
  const int t = threadIdx.x;
  const int b = p >> 5, s = p & 31, qt = 63 - s;
  const int row = g * 4 + (t >> 6);
  const int col = (t & 63) * 8;
  const size_t iA = ((size_t)(p*2 + 0)*64 + row);
  const size_t iB = ((size_t)(p*2 + 1)*64 + row);
  float mA = stats[iA*2], lA = stats[iA*2 + 1];
  float mB = stats[iB*2], lB = stats[iB*2 + 1];
  float M = fmaxf(mA, mB);
  float wA = __expf(mA - M), wB = __expf(mB - M);
  float inv = 1.f / (lA*wA + lB*wB);
  const float* pa = pO + iA * DIM + col;
  const float* pb = pO + iB * DIM + col;
  float4 a0 = ((const float4*)pa)[0], a1 = ((const float4*)pa)[1];
  float4 b0 = ((const float4*)pb)[0], b1 = ((const float4*)pb)[1];
  float* dst = out + ((size_t)b*TSEQ + (size_t)qt*64 + row) * DIM + col;
  float4 o0 = { (a0.x*wA + b0.x*wB)*inv, (a0.y*wA + b0.y*wB)*inv,
                (a0.z*wA + b0.z*wB)*inv, (a0.w*wA + b0.w*wB)*inv };
  float4 o1 = { (a1.x*wA + b1.x*wB)*inv, (a1.y*wA + b1.y*wB)*inv,
                (a1.z*wA + b1.z*wB)*inv, (a1.w*wA + b1.w*wB)*inv };
  ((float4*)dst)[0] = o0;
  ((float4*)dst)[1] = o1;
}

extern "C" void kernel_launch(void* const* d_in, const int* in_sizes, int n_in,
                              void* d_out, int out_size, void* d_ws, size_t ws_size,
                              hipStream_t stream) {
  const float* query = (const float*)d_in[0];
  const float* value = (const float*)d_in[1];
  const float* qv    = (const float*)d_in[2];
  const float* kv    = (const float*)d_in[3];
  const float* vvec  = (const float*)d_in[4];
  const float* Wq    = (const float*)d_in[5];
  const float* bq    = (const float*)d_in[6];
  const float* gam   = (const float*)d_in[7];
  const float* bet   = (const float*)d_in[8];
  const float* Ws    = (const float*)d_in[9];
  const float* bs    = (const float*)d_in[10];
  const float* Wt    = (const float*)d_in[11];
  const float* bt    = (const float*)d_in[12];
  float* out = (float*)d_out;

  char* ws = (char*)d_ws;
  float*  gq    = (float*)(ws);
  float*  gk    = (float*)(ws + 2048);
  float*  gv    = (float*)(ws + 4096);
  float*  stats = (float*)(ws + 8192);                      // 256*64*2 f32 = 128KB
  float*  qf    = (float*)(ws + 262144);                    // 32MB; reused as pO by attn2
  ushort* qb    = (ushort*)(ws + 262144 + 33554432);        // 16MB
  ushort* kb    = (ushort*)(ws + 262144 + 33554432 + 16777216);
  ushort* vT    = (ushort*)(ws + 262144 + 33554432 + 2*16777216);
  float*  pO    = qf;  // qf is dead after lnq_kernel; attn2 runs later

  gates_kernel<<<1, 512, 0, stream>>>(qv, kv, vvec, Ws, bs, Wt, bt, gq, gk, gv);
  qgemm_kernel<<<dim3(256, 8), 256, 0, stream>>>(query, Wq, bq, qf);
  lnq_kernel<<<4096, 256, 0, stream>>>(qf, gam, bet, gq, qb);
  vkprep_kernel<<<dim3(64, 8, 4), 256, 0, stream>>>(value, gk, gv, kb, vT);
  attn2_kernel<<<256, 512, 0, stream>>>(qb, kb, vT, out, pO, stats);
  comb_kernel<<<dim3(128, 16), 256, 0, stream>>>(pO, stats, out);
}